// Round 1
// baseline (349.097 us; speedup 1.0000x reference)
//
#include <hip/hip_runtime.h>

// GQA forward: X@Wq/Wk/Wv -> RoPE -> causal flash attention -> @Wo
// B=2 S=2048 HID=2048 NH=16 NKV=4 HD=128 GROUPS=4
// Strategy: bf16 MFMA (16x16x32) everywhere; threshold is bf16-sized.

typedef __attribute__((ext_vector_type(8))) short bf16x8;
typedef __attribute__((ext_vector_type(4))) float f32x4;
typedef unsigned short u16;

#define B_   2
#define S_   2048
#define HID_ 2048
#define NH_  16
#define NKV_ 4
#define HD_  128

__device__ __forceinline__ u16 f2bf(float f) {
  unsigned u = __float_as_uint(f);
  u = (u + 0x7FFFu + ((u >> 16) & 1u)) >> 16;
  return (u16)u;
}
__device__ __forceinline__ float bf2f(u16 h) {
  return __uint_as_float(((unsigned)h) << 16);
}

__device__ __forceinline__ void gl_lds16(const void* g, void* l) {
  __builtin_amdgcn_global_load_lds(
      (const __attribute__((address_space(1))) void*)g,
      (__attribute__((address_space(3))) void*)l, 16, 0, 0);
}

// ---------------- fp32 -> bf16 conversion (vectorized, 8 elems/thread) ------
__global__ void convert_bf16(const float* __restrict__ src, u16* __restrict__ dst, int n8) {
  int i = blockIdx.x * 256 + threadIdx.x;
  if (i >= n8) return;
  const float4* s = (const float4*)src + (size_t)i * 2;
  float4 a = s[0], b = s[1];
  union { u16 u[8]; uint4 v; } o;
  o.u[0] = f2bf(a.x); o.u[1] = f2bf(a.y); o.u[2] = f2bf(a.z); o.u[3] = f2bf(a.w);
  o.u[4] = f2bf(b.x); o.u[5] = f2bf(b.y); o.u[6] = f2bf(b.z); o.u[7] = f2bf(b.w);
  ((uint4*)dst)[i] = o.v;
}

// ---------------- 128x128 bf16 GEMM, C = A @ B^T (m97 structure) -----------
// A: M x K row-major bf16, Bm: N x K row-major bf16.
// EPI=0: write fp32 C[M][N].  EPI=1: scatter-QKV epilogue (bf16).
template<int EPI>
__launch_bounds__(256, 2)
__global__ void gemm128(const u16* __restrict__ A, const u16* __restrict__ Bm,
                        float* __restrict__ C, u16* __restrict__ Qb,
                        u16* __restrict__ Kb, u16* __restrict__ Vb,
                        int N, int K)
{
  __shared__ u16 As[128 * 64];
  __shared__ u16 Bs[128 * 64];
  const int tid = threadIdx.x;
  const int lane = tid & 63;
  const int w = tid >> 6;
  const int lo = lane & 15, hi = lane >> 4;
  const int wr = w >> 1, wc = w & 1;
  const int rowA0 = blockIdx.x * 128;
  const int rowB0 = blockIdx.y * 128;

  f32x4 acc[4][4] = {};

  for (int kt = 0; kt < K; kt += 64) {
    __syncthreads();
#pragma unroll
    for (int it = 0; it < 4; ++it) {
      int c = it * 256 + tid;       // 16B chunk; row = c>>3, 8 chunks/row
      int r = c >> 3;
      int cb = (c & 7) * 8;
      gl_lds16(A + (size_t)(rowA0 + r) * K + kt + cb, (char*)As + c * 16);
      gl_lds16(Bm + (size_t)(rowB0 + r) * K + kt + cb, (char*)Bs + c * 16);
    }
    __syncthreads();
#pragma unroll
    for (int kk = 0; kk < 64; kk += 32) {
      bf16x8 af[4], bfr[4];
#pragma unroll
      for (int m = 0; m < 4; ++m)
        af[m] = *(const bf16x8*)(As + (wr * 64 + m * 16 + lo) * 64 + kk + hi * 8);
#pragma unroll
      for (int n = 0; n < 4; ++n)
        bfr[n] = *(const bf16x8*)(Bs + (wc * 64 + n * 16 + lo) * 64 + kk + hi * 8);
#pragma unroll
      for (int m = 0; m < 4; ++m)
#pragma unroll
        for (int n = 0; n < 4; ++n)
          acc[m][n] = __builtin_amdgcn_mfma_f32_16x16x32_bf16(af[m], bfr[n], acc[m][n], 0, 0, 0);
    }
  }

#pragma unroll
  for (int m = 0; m < 4; ++m) {
#pragma unroll
    for (int n = 0; n < 4; ++n) {
#pragma unroll
      for (int r = 0; r < 4; ++r) {
        int grow = rowA0 + wr * 64 + m * 16 + hi * 4 + r;
        int gcol = rowB0 + wc * 64 + n * 16 + lo;
        float v = acc[m][n][r];
        if (EPI == 0) {
          C[(size_t)grow * N + gcol] = v;
        } else {
          int bb = grow >> 11, s = grow & 2047;
          u16 hv = f2bf(v);
          if (gcol < 2048) {
            int h = gcol >> 7, d = gcol & 127;
            Qb[(((size_t)bb * NH_ + h) * S_ + s) * HD_ + d] = hv;
          } else if (gcol < 2560) {
            int h = (gcol - 2048) >> 7, d = gcol & 127;
            Kb[(((size_t)bb * NKV_ + h) * S_ + s) * HD_ + d] = hv;
          } else {
            int h = (gcol - 2560) >> 7, d = gcol & 127;
            Vb[(((size_t)bb * NKV_ + h) * S_ + s) * HD_ + d] = hv;
          }
        }
      }
    }
  }
}

// ---------------- in-place RoPE on Qb and Kb (bf16) -------------------------
// layout [head_seq][S][128]; pairs (2i, 2i+1), cos/sin [S][64]
__global__ void rope_k(u16* __restrict__ Qb, u16* __restrict__ Kb,
                       const float* __restrict__ fcos, const float* __restrict__ fsin)
{
  int idx = blockIdx.x * 256 + threadIdx.x;   // 40*2048*16 chunks total
  int chunk = idx & 15;
  int s = (idx >> 4) & 2047;
  int hs = idx >> 15;                          // 0..39
  u16* p = (hs < 32) ? (Qb + ((size_t)hs * S_ + s) * HD_ + chunk * 8)
                     : (Kb + ((size_t)(hs - 32) * S_ + s) * HD_ + chunk * 8);
  uint4 raw = *(uint4*)p;
  float4 c4 = *(const float4*)(fcos + (size_t)s * 64 + chunk * 4);
  float4 s4 = *(const float4*)(fsin + (size_t)s * 64 + chunk * 4);
  float cc[4] = {c4.x, c4.y, c4.z, c4.w};
  float ss[4] = {s4.x, s4.y, s4.z, s4.w};
  unsigned* rw = (unsigned*)&raw;
#pragma unroll
  for (int j = 0; j < 4; ++j) {
    float x0 = bf2f((u16)(rw[j] & 0xFFFFu));
    float x1 = bf2f((u16)(rw[j] >> 16));
    float o0 = x0 * cc[j] - x1 * ss[j];
    float o1 = x0 * ss[j] + x1 * cc[j];
    rw[j] = (unsigned)f2bf(o0) | ((unsigned)f2bf(o1) << 16);
  }
  *(uint4*)p = raw;
}

// ---------------- causal flash attention ------------------------------------
// grid (32 qblocks, NH, B), 256 threads = 4 waves, wave w owns q rows [w*16,+16)
__launch_bounds__(256, 2)
__global__ void flash_attn(const u16* __restrict__ Qb, const u16* __restrict__ Kb,
                           const u16* __restrict__ Vb, u16* __restrict__ AO)
{
  __shared__ u16 Ks[64 * 128];   // XOR-swizzled: stored[r][slot]=orig[r][slot^(r&7)] (16B slots)
  __shared__ u16 Vt[128 * 72];   // V transposed [d][kv], padded row 72
  __shared__ u16 Ps[4][16 * 72]; // per-wave P, padded row 72

  const int tid = threadIdx.x, lane = tid & 63, w = tid >> 6;
  const int lo = lane & 15, hi = lane >> 4;
  const int qblk = blockIdx.x, h = blockIdx.y, b = blockIdx.z;
  const int kvh = h >> 2;
  const int qbase = qblk * 64;
  const u16* Qh = Qb + (((size_t)b * NH_ + h) * S_) * HD_;
  const u16* Kh = Kb + (((size_t)b * NKV_ + kvh) * S_) * HD_;
  const u16* Vh = Vb + (((size_t)b * NKV_ + kvh) * S_) * HD_;

  bf16x8 qf[4];
  const int qrow = qbase + w * 16 + lo;
#pragma unroll
  for (int kk = 0; kk < 4; ++kk)
    qf[kk] = *(const bf16x8*)(Qh + (size_t)qrow * HD_ + kk * 32 + hi * 8);

  f32x4 o[8] = {};
  float mrow[4], lrow[4];
#pragma unroll
  for (int r = 0; r < 4; ++r) { mrow[r] = -3e38f; lrow[r] = 0.f; }

  for (int t = 0; t <= qblk; ++t) {
    const int kt = t * 64;
    __syncthreads();
    // stage K (64x128) with pre-swizzled global source
#pragma unroll
    for (int it = 0; it < 4; ++it) {
      int c = it * 256 + tid;               // row = c>>4, 16 slots/row
      int r = c >> 4;
      int slot = (c & 15) ^ (r & 7);
      gl_lds16(Kh + (size_t)(kt + r) * HD_ + slot * 8, (char*)Ks + c * 16);
    }
    // stage V transposed (reg-staged; chunk mapping transposed for conflict-free writes)
#pragma unroll
    for (int it = 0; it < 4; ++it) {
      int c = it * 256 + tid;
      int kv = ((c >> 8) << 4) | (c & 15);
      int d0 = ((c >> 4) & 15) * 8;
      uint4 vv = *(const uint4*)(Vh + (size_t)(kt + kv) * HD_ + d0);
      u16* vu = (u16*)&vv;
#pragma unroll
      for (int e = 0; e < 8; ++e)
        Vt[(d0 + e) * 72 + kv] = vu[e];
    }
    __syncthreads();

    // QK^T: scores[16q][64kv] per wave
    f32x4 sc[4] = {};
#pragma unroll
    for (int kk = 0; kk < 4; ++kk) {
      bf16x8 kf[4];
#pragma unroll
      for (int n = 0; n < 4; ++n) {
        int row = n * 16 + lo;
        int slot = (kk * 4 + hi) ^ (row & 7);
        kf[n] = *(const bf16x8*)((const char*)Ks + row * 256 + slot * 16);
      }
#pragma unroll
      for (int n = 0; n < 4; ++n)
        sc[n] = __builtin_amdgcn_mfma_f32_16x16x32_bf16(qf[kk], kf[n], sc[n], 0, 0, 0);
    }

    // online softmax (row r of reg = q row hi*4+r; col = kv n*16+lo)
    const float scale = 0.08838834764831845f; // 1/sqrt(128)
    float p[4][4];
    float tmax[4];
#pragma unroll
    for (int r = 0; r < 4; ++r) tmax[r] = -3e38f;
    const bool diag = (t == qblk);
#pragma unroll
    for (int n = 0; n < 4; ++n) {
      int kv = kt + n * 16 + lo;
#pragma unroll
      for (int r = 0; r < 4; ++r) {
        float v = sc[n][r] * scale;
        if (diag && kv > qbase + w * 16 + hi * 4 + r) v = -1e9f;
        p[n][r] = v;
        tmax[r] = fmaxf(tmax[r], v);
      }
    }
#pragma unroll
    for (int d = 1; d < 16; d <<= 1)
#pragma unroll
      for (int r = 0; r < 4; ++r)
        tmax[r] = fmaxf(tmax[r], __shfl_xor(tmax[r], d));
    float resc[4], lsum[4];
#pragma unroll
    for (int r = 0; r < 4; ++r) {
      float mn = fmaxf(mrow[r], tmax[r]);
      resc[r] = __expf(mrow[r] - mn);
      mrow[r] = mn;
      lsum[r] = 0.f;
    }
#pragma unroll
    for (int n = 0; n < 4; ++n)
#pragma unroll
      for (int r = 0; r < 4; ++r) {
        float pv = __expf(p[n][r] - mrow[r]);
        p[n][r] = pv;
        lsum[r] += pv;
      }
#pragma unroll
    for (int d = 1; d < 16; d <<= 1)
#pragma unroll
      for (int r = 0; r < 4; ++r)
        lsum[r] += __shfl_xor(lsum[r], d);
#pragma unroll
    for (int r = 0; r < 4; ++r)
      lrow[r] = lrow[r] * resc[r] + lsum[r];
#pragma unroll
    for (int nf = 0; nf < 8; ++nf)
#pragma unroll
      for (int r = 0; r < 4; ++r)
        o[nf][r] *= resc[r];

    // P -> LDS (per-wave, padded)
#pragma unroll
    for (int n = 0; n < 4; ++n)
#pragma unroll
      for (int r = 0; r < 4; ++r)
        Ps[w][(hi * 4 + r) * 72 + n * 16 + lo] = f2bf(p[n][r]);

    // PV: o[16q][128d] += P(16x64) @ V(64x128)
#pragma unroll
    for (int kk2 = 0; kk2 < 64; kk2 += 32) {
      bf16x8 pa = *(const bf16x8*)(&Ps[w][lo * 72 + kk2 + hi * 8]);
#pragma unroll
      for (int nf = 0; nf < 8; ++nf) {
        bf16x8 vf = *(const bf16x8*)(&Vt[(nf * 16 + lo) * 72 + kk2 + hi * 8]);
        o[nf] = __builtin_amdgcn_mfma_f32_16x16x32_bf16(pa, vf, o[nf], 0, 0, 0);
      }
    }
  }

  // epilogue: AO[b][s][h*128+d] bf16
#pragma unroll
  for (int r = 0; r < 4; ++r) {
    float inv = 1.f / lrow[r];
    int srow = qbase + w * 16 + hi * 4 + r;
    size_t base = ((size_t)b * S_ + srow) * HID_ + (size_t)h * HD_;
#pragma unroll
    for (int nf = 0; nf < 8; ++nf)
      AO[base + nf * 16 + lo] = f2bf(o[nf][r] * inv);
  }
}

// ---------------- launcher --------------------------------------------------
extern "C" void kernel_launch(void* const* d_in, const int* in_sizes, int n_in,
                              void* d_out, int out_size, void* d_ws, size_t ws_size,
                              hipStream_t stream)
{
  (void)in_sizes; (void)n_in; (void)out_size; (void)ws_size;
  const float* X  = (const float*)d_in[0];
  const float* fc = (const float*)d_in[1];
  const float* fs = (const float*)d_in[2];
  // d_in[3] attention_mask: fixed causal mask, implemented analytically
  const float* Wq = (const float*)d_in[4];
  const float* Wk = (const float*)d_in[5];
  const float* Wv = (const float*)d_in[6];
  const float* Wo = (const float*)d_in[7];
  float* out = (float*)d_out;

  u16* Xb  = (u16*)d_ws;                        // 8M elems  (reused as AO)
  u16* Wb  = Xb + (size_t)4096 * 2048;          // 3072x2048 (reused as Wo bf16)
  u16* Qb  = Wb + (size_t)3072 * 2048;          // 8M
  u16* Kb  = Qb + (size_t)B_ * NH_ * S_ * HD_;  // 2M
  u16* Vb  = Kb + (size_t)B_ * NKV_ * S_ * HD_; // 2M
  u16* AO  = Xb;
  u16* Wob = Wb;

  // bf16 conversions
  convert_bf16<<<4096, 256, 0, stream>>>(X,  Xb,              4096 * 2048 / 8);
  convert_bf16<<<2048, 256, 0, stream>>>(Wq, Wb,              2048 * 2048 / 8);
  convert_bf16<<<512,  256, 0, stream>>>(Wk, Wb + 2048 * 2048, 512 * 2048 / 8);
  convert_bf16<<<512,  256, 0, stream>>>(Wv, Wb + 2560 * 2048, 512 * 2048 / 8);

  // QKV projection with scatter epilogue
  gemm128<1><<<dim3(32, 24), 256, 0, stream>>>(Xb, Wb, nullptr, Qb, Kb, Vb, 3072, 2048);

  // Wo conversion (reuses Wb region, dead after gemm1)
  convert_bf16<<<2048, 256, 0, stream>>>(Wo, Wob, 2048 * 2048 / 8);

  // RoPE in place on Q and K
  rope_k<<<5120, 256, 0, stream>>>(Qb, Kb, fc, fs);

  // causal flash attention -> AO (aliases Xb, dead after gemm1)
  flash_attn<<<dim3(32, NH_, B_), 256, 0, stream>>>(Qb, Kb, Vb, AO);

  // output projection -> fp32 d_out
  gemm128<0><<<dim3(32, 16), 256, 0, stream>>>(AO, Wob, out, nullptr, nullptr, nullptr, 2048, 2048);
}

// Round 2
// 232.795 us; speedup vs baseline: 1.4996x; 1.4996x over previous
//
#include <hip/hip_runtime.h>

// GQA forward: X@Wq/Wk/Wv -> RoPE -> causal flash attention -> @Wo
// B=2 S=2048 HID=2048 NH=16 NKV=4 HD=128 GROUPS=4

typedef __attribute__((ext_vector_type(8))) short bf16x8;
typedef __attribute__((ext_vector_type(4))) float f32x4;
typedef unsigned short u16;

#define B_   2
#define S_   2048
#define HID_ 2048
#define NH_  16
#define NKV_ 4
#define HD_  128

__device__ __forceinline__ u16 f2bf(float f) {
  unsigned u = __float_as_uint(f);
  u = (u + 0x7FFFu + ((u >> 16) & 1u)) >> 16;
  return (u16)u;
}
__device__ __forceinline__ float bf2f(u16 h) {
  return __uint_as_float(((unsigned)h) << 16);
}

__device__ __forceinline__ void gl_lds16(const void* g, void* l) {
  __builtin_amdgcn_global_load_lds(
      (const __attribute__((address_space(1))) void*)g,
      (__attribute__((address_space(3))) void*)l, 16, 0, 0);
}

// ---------------- fp32 -> bf16 conversion (vectorized, 8 elems/thread) ------
__global__ void convert_bf16(const float* __restrict__ src, u16* __restrict__ dst, int n8) {
  int i = blockIdx.x * 256 + threadIdx.x;
  if (i >= n8) return;
  const float4* s = (const float4*)src + (size_t)i * 2;
  float4 a = s[0], b = s[1];
  union { u16 u[8]; uint4 v; } o;
  o.u[0] = f2bf(a.x); o.u[1] = f2bf(a.y); o.u[2] = f2bf(a.z); o.u[3] = f2bf(a.w);
  o.u[4] = f2bf(b.x); o.u[5] = f2bf(b.y); o.u[6] = f2bf(b.z); o.u[7] = f2bf(b.w);
  ((uint4*)dst)[i] = o.v;
}

// ---------------- 128x128 bf16 GEMM, C = A @ B^T (m97 structure) -----------
template<int EPI>
__launch_bounds__(256, 2)
__global__ void gemm128(const u16* __restrict__ A, const u16* __restrict__ Bm,
                        float* __restrict__ C, u16* __restrict__ Qb,
                        u16* __restrict__ Kb, u16* __restrict__ Vb,
                        int N, int K)
{
  __shared__ u16 As[128 * 64];
  __shared__ u16 Bs[128 * 64];
  const int tid = threadIdx.x;
  const int lane = tid & 63;
  const int w = tid >> 6;
  const int lo = lane & 15, hi = lane >> 4;
  const int wr = w >> 1, wc = w & 1;
  const int rowA0 = blockIdx.x * 128;
  const int rowB0 = blockIdx.y * 128;

  f32x4 acc[4][4] = {};

  for (int kt = 0; kt < K; kt += 64) {
    __syncthreads();
#pragma unroll
    for (int it = 0; it < 4; ++it) {
      int c = it * 256 + tid;       // 16B chunk; row = c>>3, 8 chunks/row
      int r = c >> 3;
      int cb = (c & 7) * 8;
      gl_lds16(A + (size_t)(rowA0 + r) * K + kt + cb, (char*)As + c * 16);
      gl_lds16(Bm + (size_t)(rowB0 + r) * K + kt + cb, (char*)Bs + c * 16);
    }
    __syncthreads();
#pragma unroll
    for (int kk = 0; kk < 64; kk += 32) {
      bf16x8 af[4], bfr[4];
#pragma unroll
      for (int m = 0; m < 4; ++m)
        af[m] = *(const bf16x8*)(As + (wr * 64 + m * 16 + lo) * 64 + kk + hi * 8);
#pragma unroll
      for (int n = 0; n < 4; ++n)
        bfr[n] = *(const bf16x8*)(Bs + (wc * 64 + n * 16 + lo) * 64 + kk + hi * 8);
#pragma unroll
      for (int m = 0; m < 4; ++m)
#pragma unroll
        for (int n = 0; n < 4; ++n)
          acc[m][n] = __builtin_amdgcn_mfma_f32_16x16x32_bf16(af[m], bfr[n], acc[m][n], 0, 0, 0);
    }
  }

#pragma unroll
  for (int m = 0; m < 4; ++m) {
#pragma unroll
    for (int n = 0; n < 4; ++n) {
#pragma unroll
      for (int r = 0; r < 4; ++r) {
        int grow = rowA0 + wr * 64 + m * 16 + hi * 4 + r;
        int gcol = rowB0 + wc * 64 + n * 16 + lo;
        float v = acc[m][n][r];
        if (EPI == 0) {
          C[(size_t)grow * N + gcol] = v;
        } else {
          int bb = grow >> 11, s = grow & 2047;
          u16 hv = f2bf(v);
          if (gcol < 2048) {
            int h = gcol >> 7, d = gcol & 127;
            Qb[(((size_t)bb * NH_ + h) * S_ + s) * HD_ + d] = hv;
          } else if (gcol < 2560) {
            int h = (gcol - 2048) >> 7, d = gcol & 127;
            Kb[(((size_t)bb * NKV_ + h) * S_ + s) * HD_ + d] = hv;
          } else {
            int h = (gcol - 2560) >> 7, d = gcol & 127;
            Vb[(((size_t)bb * NKV_ + h) * S_ + s) * HD_ + d] = hv;
          }
        }
      }
    }
  }
}

// ---------------- in-place RoPE on Qb and Kb (bf16) -------------------------
__global__ void rope_k(u16* __restrict__ Qb, u16* __restrict__ Kb,
                       const float* __restrict__ fcos, const float* __restrict__ fsin)
{
  int idx = blockIdx.x * 256 + threadIdx.x;   // 40*2048*16 chunks total
  int chunk = idx & 15;
  int s = (idx >> 4) & 2047;
  int hs = idx >> 15;                          // 0..39
  u16* p = (hs < 32) ? (Qb + ((size_t)hs * S_ + s) * HD_ + chunk * 8)
                     : (Kb + ((size_t)(hs - 32) * S_ + s) * HD_ + chunk * 8);
  uint4 raw = *(uint4*)p;
  float4 c4 = *(const float4*)(fcos + (size_t)s * 64 + chunk * 4);
  float4 s4 = *(const float4*)(fsin + (size_t)s * 64 + chunk * 4);
  float cc[4] = {c4.x, c4.y, c4.z, c4.w};
  float ss[4] = {s4.x, s4.y, s4.z, s4.w};
  unsigned* rw = (unsigned*)&raw;
#pragma unroll
  for (int j = 0; j < 4; ++j) {
    float x0 = bf2f((u16)(rw[j] & 0xFFFFu));
    float x1 = bf2f((u16)(rw[j] >> 16));
    float o0 = x0 * cc[j] - x1 * ss[j];
    float o1 = x0 * ss[j] + x1 * cc[j];
    rw[j] = (unsigned)f2bf(o0) | ((unsigned)f2bf(o1) << 16);
  }
  *(uint4*)p = raw;
}

// ---------------- V transpose: Vb [hs][s][d] -> Vtg [hs][d][s] -------------
__global__ void transpose_v(const u16* __restrict__ Vb, u16* __restrict__ Vtg)
{
  __shared__ u16 t[64][65];
  const int st = blockIdx.x, dt = blockIdx.y, hs = blockIdx.z;
  const u16* src = Vb + ((size_t)hs * S_ + st * 64) * HD_ + dt * 64;
#pragma unroll
  for (int it = 0; it < 2; ++it) {
    int c = it * 256 + threadIdx.x;
    int r = c >> 3, cb = (c & 7) * 8;
    uint4 v = *(const uint4*)(src + (size_t)r * HD_ + cb);
    u16* u = (u16*)&v;
#pragma unroll
    for (int e = 0; e < 8; ++e) t[r][cb + e] = u[e];
  }
  __syncthreads();
#pragma unroll
  for (int it = 0; it < 2; ++it) {
    int c = it * 256 + threadIdx.x;
    int r2 = c >> 3, cb2 = (c & 7) * 8;
    union { u16 u[8]; uint4 v; } o;
#pragma unroll
    for (int e = 0; e < 8; ++e) o.u[e] = t[cb2 + e][r2];
    *(uint4*)(Vtg + ((size_t)hs * HD_ + dt * 64 + r2) * S_ + st * 64 + cb2) = o.v;
  }
}

// ---------------- causal flash attention ------------------------------------
// grid (16, NH, B): block handles q-tiles {x, 31-x} sequentially (balanced 33
// KV-tiles each). 256 threads = 4 waves, wave w owns q rows [w*16, w*16+16).
// K and V^T staged via global_load_lds with pre-swizzled source (XOR slot^row&7),
// double-buffered, one vmcnt(0)+barrier per KV-tile.
__launch_bounds__(256, 2)
__global__ void flash_attn(const u16* __restrict__ Qb, const u16* __restrict__ Kb,
                           const u16* __restrict__ Vtg, u16* __restrict__ AO)
{
  __shared__ u16 Ks[2][64 * 128];   // [kv][d], 16 slots/row, swizzled
  __shared__ u16 Vt[2][128 * 64];   // [d][kv], 8 slots/row, swizzled
  __shared__ u16 Ps[4][16 * 72];    // per-wave P, padded row 72

  const int tid = threadIdx.x, lane = tid & 63, w = tid >> 6;
  const int lo = lane & 15, hi = lane >> 4;
  const int h = blockIdx.y, b = blockIdx.z;
  const int kvh = h >> 2;
  const u16* Qh = Qb + (((size_t)b * NH_ + h) * S_) * HD_;
  const u16* Kh = Kb + (((size_t)b * NKV_ + kvh) * S_) * HD_;
  const u16* Vh = Vtg + (((size_t)b * NKV_ + kvh) * HD_) * S_;

  auto STAGE = [&](int buf, int kt) {
#pragma unroll
    for (int it = 0; it < 4; ++it) {          // K: 64 rows x 16 slots
      int c = it * 256 + tid;
      int r = c >> 4;
      int slot = (c & 15) ^ (r & 7);
      gl_lds16(Kh + (size_t)(kt + r) * HD_ + slot * 8, (char*)Ks[buf] + c * 16);
    }
#pragma unroll
    for (int it = 0; it < 4; ++it) {          // V^T: 128 rows x 8 slots
      int c = it * 256 + tid;
      int r = c >> 3;
      int slot = (c & 7) ^ (r & 7);
      gl_lds16(Vh + (size_t)r * S_ + kt + slot * 8, (char*)Vt[buf] + c * 16);
    }
  };

  const float scale = 0.08838834764831845f; // 1/sqrt(128)

  for (int pass = 0; pass < 2; ++pass) {
    const int qblk = pass ? (31 - (int)blockIdx.x) : (int)blockIdx.x;
    const int qbase = qblk * 64;

    bf16x8 qf[4];
    const int qrow = qbase + w * 16 + lo;
#pragma unroll
    for (int kk = 0; kk < 4; ++kk)
      qf[kk] = *(const bf16x8*)(Qh + (size_t)qrow * HD_ + kk * 32 + hi * 8);

    f32x4 o[8] = {};
    float mrow[4], lrow[4];
#pragma unroll
    for (int r = 0; r < 4; ++r) { mrow[r] = -3e38f; lrow[r] = 0.f; }

    __syncthreads();                 // prior pass done with LDS
    STAGE(0, 0);
    asm volatile("s_waitcnt vmcnt(0)" ::: "memory");
    __syncthreads();
    int cur = 0;

    for (int t = 0; t <= qblk; ++t) {
      if (t < qblk) STAGE(cur ^ 1, (t + 1) * 64);
      const int kt = t * 64;

      // QK^T: scores[16q][64kv] per wave
      f32x4 sc[4] = {};
      __builtin_amdgcn_s_setprio(1);
#pragma unroll
      for (int kk = 0; kk < 4; ++kk) {
        bf16x8 kf[4];
#pragma unroll
        for (int n = 0; n < 4; ++n) {
          int row = n * 16 + lo;
          int slot = (kk * 4 + hi) ^ (row & 7);
          kf[n] = *(const bf16x8*)((const char*)Ks[cur] + row * 256 + slot * 16);
        }
#pragma unroll
        for (int n = 0; n < 4; ++n)
          sc[n] = __builtin_amdgcn_mfma_f32_16x16x32_bf16(qf[kk], kf[n], sc[n], 0, 0, 0);
      }
      __builtin_amdgcn_s_setprio(0);

      // online softmax (reg row r = q row hi*4+r; col = kv n*16+lo)
      float p[4][4];
      float tmax[4];
#pragma unroll
      for (int r = 0; r < 4; ++r) tmax[r] = -3e38f;
      const bool diag = (t == qblk);
#pragma unroll
      for (int n = 0; n < 4; ++n) {
        int kv = kt + n * 16 + lo;
#pragma unroll
        for (int r = 0; r < 4; ++r) {
          float v = sc[n][r] * scale;
          if (diag && kv > qbase + w * 16 + hi * 4 + r) v = -1e9f;
          p[n][r] = v;
          tmax[r] = fmaxf(tmax[r], v);
        }
      }
#pragma unroll
      for (int d = 1; d < 16; d <<= 1)
#pragma unroll
        for (int r = 0; r < 4; ++r)
          tmax[r] = fmaxf(tmax[r], __shfl_xor(tmax[r], d));
      float resc[4], lsum[4];
#pragma unroll
      for (int r = 0; r < 4; ++r) {
        float mn = fmaxf(mrow[r], tmax[r]);
        resc[r] = __expf(mrow[r] - mn);
        mrow[r] = mn;
        lsum[r] = 0.f;
      }
#pragma unroll
      for (int n = 0; n < 4; ++n)
#pragma unroll
        for (int r = 0; r < 4; ++r) {
          float pv = __expf(p[n][r] - mrow[r]);
          p[n][r] = pv;
          lsum[r] += pv;
        }
#pragma unroll
      for (int d = 1; d < 16; d <<= 1)
#pragma unroll
        for (int r = 0; r < 4; ++r)
          lsum[r] += __shfl_xor(lsum[r], d);
#pragma unroll
      for (int r = 0; r < 4; ++r)
        lrow[r] = lrow[r] * resc[r] + lsum[r];
#pragma unroll
      for (int nf = 0; nf < 8; ++nf)
#pragma unroll
        for (int r = 0; r < 4; ++r)
          o[nf][r] *= resc[r];

      // P -> LDS (per-wave, padded)
#pragma unroll
      for (int n = 0; n < 4; ++n)
#pragma unroll
        for (int r = 0; r < 4; ++r)
          Ps[w][(hi * 4 + r) * 72 + n * 16 + lo] = f2bf(p[n][r]);

      // PV: o[16q][128d] += P(16x64) @ V(64x128)
      __builtin_amdgcn_s_setprio(1);
#pragma unroll
      for (int kk2 = 0; kk2 < 64; kk2 += 32) {
        bf16x8 pa = *(const bf16x8*)(&Ps[w][lo * 72 + kk2 + hi * 8]);
#pragma unroll
        for (int nf = 0; nf < 8; ++nf) {
          int row = nf * 16 + lo;
          int slot = ((kk2 >> 3) + hi) ^ (row & 7);
          bf16x8 vf = *(const bf16x8*)((const char*)Vt[cur] + row * 128 + slot * 16);
          o[nf] = __builtin_amdgcn_mfma_f32_16x16x32_bf16(pa, vf, o[nf], 0, 0, 0);
        }
      }
      __builtin_amdgcn_s_setprio(0);

      asm volatile("s_waitcnt vmcnt(0)" ::: "memory");
      __syncthreads();
      cur ^= 1;
    }

    // epilogue: AO[b][s][h*128+d] bf16
#pragma unroll
    for (int r = 0; r < 4; ++r) {
      float inv = 1.f / lrow[r];
      int srow = qbase + w * 16 + hi * 4 + r;
      size_t base = ((size_t)b * S_ + srow) * HID_ + (size_t)h * HD_;
#pragma unroll
      for (int nf = 0; nf < 8; ++nf)
        AO[base + nf * 16 + lo] = f2bf(o[nf][r] * inv);
    }
  }
}

// ---------------- launcher --------------------------------------------------
extern "C" void kernel_launch(void* const* d_in, const int* in_sizes, int n_in,
                              void* d_out, int out_size, void* d_ws, size_t ws_size,
                              hipStream_t stream)
{
  (void)in_sizes; (void)n_in; (void)out_size; (void)ws_size;
  const float* X  = (const float*)d_in[0];
  const float* fc = (const float*)d_in[1];
  const float* fs = (const float*)d_in[2];
  // d_in[3] attention_mask: fixed causal mask, implemented analytically
  const float* Wq = (const float*)d_in[4];
  const float* Wk = (const float*)d_in[5];
  const float* Wv = (const float*)d_in[6];
  const float* Wo = (const float*)d_in[7];
  float* out = (float*)d_out;

  u16* Xb  = (u16*)d_ws;                        // 8M elems (reused as AO)
  u16* Wb  = Xb + (size_t)4096 * 2048;          // 3072x2048 (reused: Wob + Vtg)
  u16* Qb  = Wb + (size_t)3072 * 2048;          // 8M
  u16* Kb  = Qb + (size_t)B_ * NH_ * S_ * HD_;  // 2M
  u16* Vb  = Kb + (size_t)B_ * NKV_ * S_ * HD_; // 2M
  u16* AO  = Xb;
  u16* Wob = Wb;                                // 4M elems
  u16* Vtg = Wb + (size_t)2048 * 2048;          // 2M elems (spare tail of Wb)

  // bf16 conversions
  convert_bf16<<<4096, 256, 0, stream>>>(X,  Xb,               4096 * 2048 / 8);
  convert_bf16<<<2048, 256, 0, stream>>>(Wq, Wb,               2048 * 2048 / 8);
  convert_bf16<<<512,  256, 0, stream>>>(Wk, Wb + 2048 * 2048, 512 * 2048 / 8);
  convert_bf16<<<512,  256, 0, stream>>>(Wv, Wb + 2560 * 2048, 512 * 2048 / 8);

  // QKV projection with scatter epilogue
  gemm128<1><<<dim3(32, 24), 256, 0, stream>>>(Xb, Wb, nullptr, Qb, Kb, Vb, 3072, 2048);

  // Wo conversion (reuses Wb[0:4M], dead after gemm1)
  convert_bf16<<<2048, 256, 0, stream>>>(Wo, Wob, 2048 * 2048 / 8);

  // V transpose into Vtg [hs][128][2048] (Wb spare tail, dead after gemm1)
  transpose_v<<<dim3(32, 2, 8), 256, 0, stream>>>(Vb, Vtg);

  // RoPE in place on Q and K
  rope_k<<<5120, 256, 0, stream>>>(Qb, Kb, fc, fs);

  // causal flash attention -> AO (aliases Xb, dead after gemm1)
  flash_attn<<<dim3(16, NH_, B_), 256, 0, stream>>>(Qb, Kb, Vtg, AO);

  // output projection -> fp32 d_out
  gemm128<0><<<dim3(32, 16), 256, 0, stream>>>(AO, Wob, out, nullptr, nullptr, nullptr, 2048, 2048);
}